// Round 5
// baseline (384.095 us; speedup 1.0000x reference)
//
#include <hip/hip_runtime.h>
#include <hip/hip_bf16.h>

// ---------------------------------------------------------------------------
// FakeFlexOlmoSparseMlp: top-2 MoE over 8 experts, H=1024, 8192 tokens.
// R5: barrier-free register-direct GEMM. R4 post-mortem: 4x off every
// roofline, pure exposed vmcnt(0)-at-barrier latency (structural). Both
// operands pre-swizzled to MFMA-fragment chunk order -> per-lane
// global_load_dwordx4 straight to registers, zero LDS/barriers in K-loop,
// explicit ping-pong prefetch. Weight swizzle fused into router dispatch.
// ---------------------------------------------------------------------------

#define HD   1024
#define NTOK 8192
#define NEXP 8
#define BM   128
#define BN   128
#define ZROW 8192     // sentinel row in x_bf16 filled with zeros (pad slots)
#define MAXP 17408    // 16384 pairs + 8*128 max padding = 136 tiles of 128
#define EP_LDSW 136   // epilogue LDS row stride (shorts); 272B = 16B-aligned
#define RB   256      // router blocks inside prep_kernel

typedef __attribute__((ext_vector_type(8))) short  vshort8;
typedef __attribute__((ext_vector_type(4))) short  vshort4;
typedef __attribute__((ext_vector_type(4))) float  vfloat4;

__device__ __forceinline__ short bf16r(float f) {
    union { float f; unsigned u; } a; a.f = f;
    unsigned r = a.u + 0x7FFFu + ((a.u >> 16) & 1u);   // round-to-nearest-even
    return (short)(r >> 16);
}

// --- K1: zero meta, pair_token -> ZROW sentinel, zero the ZROW row ---------
__global__ void init_kernel(int* counts, int* fill, int* pair_token, short* xb) {
    int i = blockIdx.x * 256 + threadIdx.x;
    if (i < NEXP) { counts[i] = 0; fill[i] = 0; }
    if (i < MAXP) pair_token[i] = ZROW;
    if (i < HD / 8) {
        vshort8 z = {0, 0, 0, 0, 0, 0, 0, 0};
        *(vshort8*)(xb + (size_t)ZROW * HD + i * 8) = z;
    }
}

// --- K2: prep = router (blocks 0..RB-1) + weight swizzle (blocks RB..) -----
// Router: 32 tokens/block, fused residual-copy + bf16 cast + probs + top2 +
// LDS-aggregated counts. Swizzle: fp32 W -> bf16 fragment-chunk order.
// Chunk C = ((e*64+ng)*32+kc); lane l = quad*16+l16 holds
// W[e][ng*16+l16][kc*32+quad*8 .. +7]. Reads fully coalesced (thread u reads
// 8 contiguous fp32 at u*8), writes 16B-scattered (L2-buffered).
__global__ __launch_bounds__(256) void prep_kernel(
    const float* __restrict__ x, const float* __restrict__ rw,
    const float* __restrict__ W1, const float* __restrict__ W2,
    float* __restrict__ out, short* __restrict__ xb,
    float* __restrict__ probs_out, int2* __restrict__ tok_top,
    float2* __restrict__ tok_w, int* __restrict__ counts,
    short* __restrict__ w1sw, short* __restrict__ w2sw) {
    __shared__ float rws[NEXP * HD];
    __shared__ int hist[NEXP];
    int t = threadIdx.x;
    if (blockIdx.x >= RB) {
        // ---- weight swizzle path ----
        size_t u = (size_t)(blockIdx.x - RB) * 256 + t;
        const size_t PER = (size_t)NEXP * HD * HD / 8;   // threads per matrix
        const float* src = W1; short* dst = w1sw;
        if (u >= PER) { u -= PER; src = W2; dst = w2sw; }
        size_t s = u * 8;                 // linear fp32 index, 8 contiguous
        int e  = (int)(s >> 20);
        int n  = (int)((s >> 10) & 1023);
        int k  = (int)(s & 1023);
        vfloat4 a = *(const vfloat4*)(src + s);
        vfloat4 b = *(const vfloat4*)(src + s + 4);
        vshort8 o;
        o[0] = bf16r(a.x); o[1] = bf16r(a.y); o[2] = bf16r(a.z); o[3] = bf16r(a.w);
        o[4] = bf16r(b.x); o[5] = bf16r(b.y); o[6] = bf16r(b.z); o[7] = bf16r(b.w);
        size_t chunk = ((size_t)e * 64 + (n >> 4)) * 32 + (k >> 5);
        int lane = ((k >> 3) & 3) * 16 + (n & 15);
        *(vshort8*)(dst + chunk * 512 + lane * 8) = o;
        return;
    }
    // ---- router path ----
    if (t < NEXP) hist[t] = 0;
    for (int j = 0; j < 8; ++j) {
        int idx = j * 1024 + t * 4;
        *(vfloat4*)(rws + idx) = *(const vfloat4*)(rw + idx);
    }
    __syncthreads();
    int wave = t >> 6, lane = t & 63;
    for (int it = 0; it < 8; ++it) {
        int token = blockIdx.x * 32 + it * 4 + wave;
        const float* xr = x + (size_t)token * HD;
        float part[NEXP];
#pragma unroll
        for (int e = 0; e < NEXP; ++e) part[e] = 0.f;
        for (int j = 0; j < 4; ++j) {
            int off = j * 256 + lane * 4;
            vfloat4 xv = *(const vfloat4*)(xr + off);
            *(vfloat4*)(out + (size_t)token * HD + off) = xv;   // residual init
            vshort4 bq;
            bq.x = bf16r(xv.x); bq.y = bf16r(xv.y); bq.z = bf16r(xv.z); bq.w = bf16r(xv.w);
            *(vshort4*)(xb + (size_t)token * HD + off) = bq;
#pragma unroll
            for (int e = 0; e < NEXP; ++e) {
                vfloat4 wv = *(const vfloat4*)(rws + e * HD + off);
                part[e] += xv.x * wv.x + xv.y * wv.y + xv.z * wv.z + xv.w * wv.w;
            }
        }
#pragma unroll
        for (int e = 0; e < NEXP; ++e)
            for (int off = 32; off; off >>= 1)
                part[e] += __shfl_xor(part[e], off, 64);
        if (lane == 0) {
            float m = part[0];
#pragma unroll
            for (int e = 1; e < NEXP; ++e) m = fmaxf(m, part[e]);
            float p[NEXP], s = 0.f;
#pragma unroll
            for (int e = 0; e < NEXP; ++e) { p[e] = expf(part[e] - m); s += p[e]; }
            float inv = 1.f / s;
#pragma unroll
            for (int e = 0; e < NEXP; ++e) {
                p[e] *= inv;
                probs_out[(size_t)token * NEXP + e] = p[e];
            }
            int i0 = 0;
#pragma unroll
            for (int e = 1; e < NEXP; ++e) if (p[e] > p[i0]) i0 = e;  // ties -> lowest idx
            int i1 = (i0 == 0) ? 1 : 0;
#pragma unroll
            for (int e = 0; e < NEXP; ++e) if (e != i0 && p[e] > p[i1]) i1 = e;
            float s2 = 1.f / (p[i0] + p[i1]);
            tok_top[token] = make_int2(i0, i1);
            tok_w[token]   = make_float2(p[i0] * s2, p[i1] * s2);
            atomicAdd(&hist[i0], 1);
            atomicAdd(&hist[i1], 1);
        }
    }
    __syncthreads();
    if (t < NEXP) atomicAdd(&counts[t], hist[t]);
}

// --- K3: scatter pairs into expert buckets (inline offsets from counts) ----
__global__ __launch_bounds__(256) void scatter_kernel(
    const int2* __restrict__ tok_top, const float2* __restrict__ tok_w,
    const int* __restrict__ counts, int* fill,
    int* __restrict__ pair_token, float* __restrict__ pair_w) {
    __shared__ int lhist[NEXP];
    __shared__ int lbase[NEXP];
    int t = threadIdx.x;
    if (t < NEXP) lhist[t] = 0;
    __syncthreads();
    int offs[NEXP];
    {
        int acc = 0;
#pragma unroll
        for (int f = 0; f < NEXP; ++f) {
            offs[f] = acc;
            acc += (counts[f] + 127) & ~127;
        }
    }
    int token = blockIdx.x * 256 + t;
    int2 ti = tok_top[token];
    float2 tw = tok_w[token];
    int r0 = atomicAdd(&lhist[ti.x], 1);
    int r1 = atomicAdd(&lhist[ti.y], 1);
    __syncthreads();
    if (t < NEXP) lbase[t] = atomicAdd(&fill[t], lhist[t]);
    __syncthreads();
    int s0 = offs[ti.x] + lbase[ti.x] + r0;
    pair_token[s0] = token; pair_w[s0] = tw.x;
    int s1 = offs[ti.y] + lbase[ti.y] + r1;
    pair_token[s1] = token; pair_w[s1] = tw.y;
}

// --- K4/K5: barrier-free register-direct grouped NT-GEMM -------------------
// Block 128x128, 4 waves in 2x2; wave tile 64x64, acc[4][4].
// All fragments loaded per-lane from global (chunk order), ping-pong prefetch.
// MODE 0: A = xb row-major gathered via pair_token (16x64B segments/load);
//         epilogue relu(acc+b1) -> LDS transpose -> chunk-ordered h1sw.
// MODE 1: A = h1sw chunk-ordered (1KB/wave coalesced); no LDS at all;
//         epilogue atomicAdd out += w*(acc+b2).
template <int MODE>
__global__ __launch_bounds__(256, 2) void moe_gemm(
    const short* __restrict__ A, const short* __restrict__ Bw,
    const float* __restrict__ bias, const int* __restrict__ pair_token,
    const float* __restrict__ pair_w, const int* __restrict__ counts,
    short* __restrict__ h1sw_out, float* __restrict__ out) {
    __shared__ short smem[(MODE == 0) ? (BM * EP_LDSW) : 16];

    const int row0 = blockIdx.x * BM;
    int e = 0;
    {
        int csum = 0;
#pragma unroll
        for (int f = 0; f < NEXP; ++f) {
            int p = (counts[f] + 127) & ~127;
            if (csum + p <= row0) e = f + 1;
            csum += p;
        }
        if (row0 >= csum) return;       // past padded total
    }

    const int t = threadIdx.x;
    const int wave = t >> 6, lane = t & 63;
    const int wm = wave >> 1, wn = wave & 1;
    const int quad = lane >> 4, l16 = lane & 15;
    const int colb = blockIdx.y * BN;

    // per-lane fragment base pointers (kc = 0)
    const short* aRow[4];
#pragma unroll
    for (int i = 0; i < 4; ++i) {
        if (MODE == 0) {
            int tok = pair_token[row0 + wm * 64 + i * 16 + l16];
            aRow[i] = A + (size_t)tok * HD + quad * 8;          // +kc*32
        } else {
            aRow[i] = A + ((size_t)(row0 >> 4) + wm * 4 + i) * 16384 + lane * 8;  // +kc*512
        }
    }
    const short* bRow[4];
#pragma unroll
    for (int j = 0; j < 4; ++j)
        bRow[j] = Bw + ((size_t)e * 64 + (colb >> 4) + wn * 4 + j) * 16384 + lane * 8;  // +kc*512

    vfloat4 acc[4][4];
#pragma unroll
    for (int i = 0; i < 4; ++i)
#pragma unroll
        for (int j = 0; j < 4; ++j)
            acc[i][j] = (vfloat4){0.f, 0.f, 0.f, 0.f};

    vshort8 aP[4], bP[4], aN[4], bN[4];
#pragma unroll
    for (int i = 0; i < 4; ++i) {
        aP[i] = *(const vshort8*)(aRow[i]);
        bP[i] = *(const vshort8*)(bRow[i]);
    }
#pragma unroll 4
    for (int kc = 0; kc < 32; ++kc) {
        if (kc < 31) {
#pragma unroll
            for (int i = 0; i < 4; ++i) {
                aN[i] = *(const vshort8*)(aRow[i] + (MODE == 0 ? (kc + 1) * 32 : (kc + 1) * 512));
                bN[i] = *(const vshort8*)(bRow[i] + (kc + 1) * 512);
            }
        }
#pragma unroll
        for (int i = 0; i < 4; ++i)
#pragma unroll
            for (int j = 0; j < 4; ++j)
                acc[i][j] = __builtin_amdgcn_mfma_f32_16x16x32_bf16(aP[i], bP[j], acc[i][j], 0, 0, 0);
#pragma unroll
        for (int i = 0; i < 4; ++i) { aP[i] = aN[i]; bP[i] = bN[i]; }
    }

    if (MODE == 0) {
        // epilogue: relu(acc+b1) -> bf16 LDS tile -> chunk-ordered h1sw
#pragma unroll
        for (int j = 0; j < 4; ++j) {
            int col = wn * 64 + j * 16 + l16;
            float bv = bias[e * HD + colb + col];
#pragma unroll
            for (int i = 0; i < 4; ++i) {
                int rl = wm * 64 + i * 16 + quad * 4;
#pragma unroll
                for (int reg = 0; reg < 4; ++reg) {
                    float v = acc[i][j][reg] + bv;
                    v = v > 0.f ? v : 0.f;
                    smem[(rl + reg) * EP_LDSW + col] = bf16r(v);
                }
            }
        }
        __syncthreads();
#pragma unroll
        for (int u = 0; u < 2; ++u) {
            int sgl = wave * 2 + u;              // rowgroup 0..7
            int lrow = sgl * 16 + l16;
#pragma unroll
            for (int kk = 0; kk < 4; ++kk) {
                vshort8 v = *(const vshort8*)(smem + lrow * EP_LDSW + kk * 32 + quad * 8);
                size_t chunk = ((size_t)((row0 >> 4) + sgl) * 32) + ((colb >> 5) + kk);
                *(vshort8*)(h1sw_out + chunk * 512 + lane * 8) = v;
            }
        }
    } else {
        int tok[4][4]; float wv[4][4];
#pragma unroll
        for (int i = 0; i < 4; ++i)
#pragma unroll
            for (int reg = 0; reg < 4; ++reg) {
                int r = row0 + wm * 64 + i * 16 + quad * 4 + reg;
                tok[i][reg] = pair_token[r];
                wv[i][reg] = pair_w[r];
            }
#pragma unroll
        for (int j = 0; j < 4; ++j) {
            int col = colb + wn * 64 + j * 16 + l16;
            float bv = bias[e * HD + col];
#pragma unroll
            for (int i = 0; i < 4; ++i)
#pragma unroll
                for (int reg = 0; reg < 4; ++reg)
                    if (tok[i][reg] < ZROW)
                        atomicAdd(out + (size_t)tok[i][reg] * HD + col,
                                  wv[i][reg] * (acc[i][j][reg] + bv));
        }
    }
}

extern "C" void kernel_launch(void* const* d_in, const int* in_sizes, int n_in,
                              void* d_out, int out_size, void* d_ws, size_t ws_size,
                              hipStream_t stream) {
    const float* x  = (const float*)d_in[0];
    const float* rw = (const float*)d_in[1];
    const float* W1 = (const float*)d_in[2];
    const float* b1 = (const float*)d_in[3];
    const float* W2 = (const float*)d_in[4];
    const float* b2 = (const float*)d_in[5];
    float* out   = (float*)d_out;                // [8192,1024] residual+moe
    float* probs = out + (size_t)NTOK * HD;      // [8192,8]

    char* ws = (char*)d_ws;
    short* xb = (short*)ws;            ws += (size_t)(NTOK + 1) * HD * 2;
    short* h1 = (short*)ws;            ws += (size_t)MAXP * HD * 2;
    int*   pair_token = (int*)ws;      ws += MAXP * 4;
    float* pair_w     = (float*)ws;    ws += MAXP * 4;
    int*   counts = (int*)ws;          ws += 256;
    int*   fill   = (int*)ws;          ws += 256;
    int2*   tok_top = (int2*)ws;       ws += NTOK * 8;
    float2* tok_w   = (float2*)ws;     ws += NTOK * 8;
    short* w1sw = (short*)ws;          ws += (size_t)NEXP * HD * HD * 2;
    short* w2sw = (short*)ws;          ws += (size_t)NEXP * HD * HD * 2;
    (void)ws_size;

    init_kernel<<<MAXP / 256, 256, 0, stream>>>(counts, fill, pair_token, xb);
    int swb = (int)(2 * ((size_t)NEXP * HD * HD / 8) / 256);    // 8192 swizzle blocks
    prep_kernel<<<RB + swb, 256, 0, stream>>>(x, rw, W1, W2, out, xb, probs,
                                              tok_top, tok_w, counts, w1sw, w2sw);
    scatter_kernel<<<NTOK / 256, 256, 0, stream>>>(tok_top, tok_w, counts, fill,
                                                   pair_token, pair_w);
    dim3 gg(MAXP / BM, HD / BN);       // 136 x 8; blocks past padded total exit
    moe_gemm<0><<<gg, 256, 0, stream>>>(xb, w1sw, b1, pair_token, pair_w, counts, h1, nullptr);
    moe_gemm<1><<<gg, 256, 0, stream>>>(h1, w2sw, b2, pair_token, pair_w, counts, nullptr, out);
}

// Round 6
// 378.388 us; speedup vs baseline: 1.0151x; 1.0151x over previous
//
#include <hip/hip_runtime.h>
#include <hip/hip_bf16.h>

// ---------------------------------------------------------------------------
// FakeFlexOlmoSparseMlp: top-2 MoE over 8 experts, H=1024, 8192 tokens.
// R6: back to shared-LDS async staging (R5 register-direct regressed: 2x L2
// traffic + shallow prefetch + VGPR pressure). BK=128 -> 64 MFMA/wave per
// barrier (8 drains instead of 16). Weights staged directly from row-major
// bf16 via per-lane gld16 addresses (no chunk swizzle needed; LDS side is the
// only uniform+lane*16 constraint). h1 row-major. XCD-aware block swizzle:
// a row-tile's 8 column blocks share an XCD's L2 for the A tile.
// ---------------------------------------------------------------------------

#define HD   1024
#define NTOK 8192
#define NEXP 8
#define BM   128
#define BN   128
#define ZROW 8192     // sentinel row in x_bf16 filled with zeros (pad slots)
#define MAXP 17408    // 16384 pairs + 8*128 max padding = 136 tiles of 128
#define EP_LDSW 136   // epilogue LDS row stride (shorts); 272B = 16B-aligned
#define RB   256      // router blocks inside prep_kernel

typedef __attribute__((ext_vector_type(8))) short  vshort8;
typedef __attribute__((ext_vector_type(4))) short  vshort4;
typedef __attribute__((ext_vector_type(4))) float  vfloat4;

typedef __attribute__((address_space(1))) const unsigned gas_uint;
typedef __attribute__((address_space(3))) unsigned       las_uint;

__device__ __forceinline__ void gld16(const void* g, void* l) {
    // async global->LDS, 16B/lane; LDS dest = wave-uniform base + lane*16,
    // global src may be fully per-lane (gather).
    __builtin_amdgcn_global_load_lds((gas_uint*)g, (las_uint*)l, 16, 0, 0);
}

__device__ __forceinline__ short bf16r(float f) {
    union { float f; unsigned u; } a; a.f = f;
    unsigned r = a.u + 0x7FFFu + ((a.u >> 16) & 1u);   // round-to-nearest-even
    return (short)(r >> 16);
}

// --- K1: zero meta, pair_token -> ZROW sentinel, zero the ZROW row ---------
__global__ void init_kernel(int* counts, int* fill, int* pair_token, short* xb) {
    int i = blockIdx.x * 256 + threadIdx.x;
    if (i < NEXP) { counts[i] = 0; fill[i] = 0; }
    if (i < MAXP) pair_token[i] = ZROW;
    if (i < HD / 8) {
        vshort8 z = {0, 0, 0, 0, 0, 0, 0, 0};
        *(vshort8*)(xb + (size_t)ZROW * HD + i * 8) = z;
    }
}

// --- K2: prep = router (blocks 0..RB-1) + W1/W2 bf16 convert (blocks RB..) -
__global__ __launch_bounds__(256) void prep_kernel(
    const float* __restrict__ x, const float* __restrict__ rw,
    const float* __restrict__ W1, const float* __restrict__ W2,
    float* __restrict__ out, short* __restrict__ xb,
    float* __restrict__ probs_out, int2* __restrict__ tok_top,
    float2* __restrict__ tok_w, int* __restrict__ counts,
    short* __restrict__ w1b, short* __restrict__ w2b) {
    __shared__ float rws[NEXP * HD];
    __shared__ int hist[NEXP];
    int t = threadIdx.x;
    if (blockIdx.x >= RB) {
        // ---- plain coalesced fp32 -> bf16 weight convert ----
        size_t u = (size_t)(blockIdx.x - RB) * 256 + t;
        const size_t PER = (size_t)NEXP * HD * HD / 8;   // threads per matrix
        const float* src = W1; short* dst = w1b;
        if (u >= PER) { u -= PER; src = W2; dst = w2b; }
        size_t s = u * 8;
        vfloat4 a = *(const vfloat4*)(src + s);
        vfloat4 b = *(const vfloat4*)(src + s + 4);
        vshort8 o;
        o[0] = bf16r(a.x); o[1] = bf16r(a.y); o[2] = bf16r(a.z); o[3] = bf16r(a.w);
        o[4] = bf16r(b.x); o[5] = bf16r(b.y); o[6] = bf16r(b.z); o[7] = bf16r(b.w);
        *(vshort8*)(dst + s) = o;
        return;
    }
    // ---- router path: 32 tokens/block, fused residual copy + bf16 cast ----
    if (t < NEXP) hist[t] = 0;
    for (int j = 0; j < 8; ++j) {
        int idx = j * 1024 + t * 4;
        *(vfloat4*)(rws + idx) = *(const vfloat4*)(rw + idx);
    }
    __syncthreads();
    int wave = t >> 6, lane = t & 63;
    for (int it = 0; it < 8; ++it) {
        int token = blockIdx.x * 32 + it * 4 + wave;
        const float* xr = x + (size_t)token * HD;
        float part[NEXP];
#pragma unroll
        for (int e = 0; e < NEXP; ++e) part[e] = 0.f;
        for (int j = 0; j < 4; ++j) {
            int off = j * 256 + lane * 4;
            vfloat4 xv = *(const vfloat4*)(xr + off);
            *(vfloat4*)(out + (size_t)token * HD + off) = xv;   // residual init
            vshort4 bq;
            bq.x = bf16r(xv.x); bq.y = bf16r(xv.y); bq.z = bf16r(xv.z); bq.w = bf16r(xv.w);
            *(vshort4*)(xb + (size_t)token * HD + off) = bq;
#pragma unroll
            for (int e = 0; e < NEXP; ++e) {
                vfloat4 wv = *(const vfloat4*)(rws + e * HD + off);
                part[e] += xv.x * wv.x + xv.y * wv.y + xv.z * wv.z + xv.w * wv.w;
            }
        }
#pragma unroll
        for (int e = 0; e < NEXP; ++e)
            for (int off = 32; off; off >>= 1)
                part[e] += __shfl_xor(part[e], off, 64);
        if (lane == 0) {
            float m = part[0];
#pragma unroll
            for (int e = 1; e < NEXP; ++e) m = fmaxf(m, part[e]);
            float p[NEXP], s = 0.f;
#pragma unroll
            for (int e = 0; e < NEXP; ++e) { p[e] = expf(part[e] - m); s += p[e]; }
            float inv = 1.f / s;
#pragma unroll
            for (int e = 0; e < NEXP; ++e) {
                p[e] *= inv;
                probs_out[(size_t)token * NEXP + e] = p[e];
            }
            int i0 = 0;
#pragma unroll
            for (int e = 1; e < NEXP; ++e) if (p[e] > p[i0]) i0 = e;  // ties -> lowest idx
            int i1 = (i0 == 0) ? 1 : 0;
#pragma unroll
            for (int e = 0; e < NEXP; ++e) if (e != i0 && p[e] > p[i1]) i1 = e;
            float s2 = 1.f / (p[i0] + p[i1]);
            tok_top[token] = make_int2(i0, i1);
            tok_w[token]   = make_float2(p[i0] * s2, p[i1] * s2);
            atomicAdd(&hist[i0], 1);
            atomicAdd(&hist[i1], 1);
        }
    }
    __syncthreads();
    if (t < NEXP) atomicAdd(&counts[t], hist[t]);
}

// --- K3: scatter pairs into expert buckets (inline offsets from counts) ----
__global__ __launch_bounds__(256) void scatter_kernel(
    const int2* __restrict__ tok_top, const float2* __restrict__ tok_w,
    const int* __restrict__ counts, int* fill,
    int* __restrict__ pair_token, float* __restrict__ pair_w) {
    __shared__ int lhist[NEXP];
    __shared__ int lbase[NEXP];
    int t = threadIdx.x;
    if (t < NEXP) lhist[t] = 0;
    __syncthreads();
    int offs[NEXP];
    {
        int acc = 0;
#pragma unroll
        for (int f = 0; f < NEXP; ++f) {
            offs[f] = acc;
            acc += (counts[f] + 127) & ~127;
        }
    }
    int token = blockIdx.x * 256 + t;
    int2 ti = tok_top[token];
    float2 tw = tok_w[token];
    int r0 = atomicAdd(&lhist[ti.x], 1);
    int r1 = atomicAdd(&lhist[ti.y], 1);
    __syncthreads();
    if (t < NEXP) lbase[t] = atomicAdd(&fill[t], lhist[t]);
    __syncthreads();
    int s0 = offs[ti.x] + lbase[ti.x] + r0;
    pair_token[s0] = token; pair_w[s0] = tw.x;
    int s1 = offs[ti.y] + lbase[ti.y] + r1;
    pair_token[s1] = token; pair_w[s1] = tw.y;
}

// --- K4/K5: grouped NT-GEMM, BK=128, 4 waves, async fragment staging -------
// 1D grid, XCD swizzle: lin = xcd + 8*(colblk + 8*rsup), rowtile = rsup*8+xcd
// -> the 8 column blocks of one row tile land on one XCD (L2-shared A tile).
// LDS 64KB: A chunks [(g*4+kc)*512], B at +16384 shorts. Chunk = 16 rows x
// 32 k, lane(quad,l16) holds [row g*16+l16][k kc*32+quad*8 ..+7] = gld16 with
// per-lane global gather from row-major source.
// MODE 0: A rows via pair_token; epi relu(acc+b1) -> LDS transpose ->
//         row-major h1 (coalesced). MODE 1: A = h1 rows; epi atomic combine.
template <int MODE>
__global__ __launch_bounds__(256, 2) void moe_gemm(
    const short* __restrict__ A, const short* __restrict__ Bw,
    const float* __restrict__ bias, const int* __restrict__ pair_token,
    const float* __restrict__ pair_w, const int* __restrict__ counts,
    short* __restrict__ h1_out, float* __restrict__ out) {
    __shared__ short smem[32768];          // 64 KB

    const int lin = blockIdx.x;
    const int xcd = lin & 7;
    const int cb  = (lin >> 3) & 7;
    const int rt  = (lin >> 6) * 8 + xcd;  // 0..135
    const int row0 = rt * BM;
    const int colb = cb * BN;

    int e = 0;
    {
        int csum = 0;
#pragma unroll
        for (int f = 0; f < NEXP; ++f) {
            int p = (counts[f] + 127) & ~127;
            if (csum + p <= row0) e = f + 1;
            csum += p;
        }
        if (row0 >= csum) return;          // past padded total
    }

    const int t = threadIdx.x;
    const int wave = t >> 6, lane = t & 63;
    const int wm = wave >> 1, wn = wave & 1;
    const int quad = lane >> 4, l16 = lane & 15;

    // per-lane global base pointers for this wave's staged groups g=2w,2w+1
    const char* agp[2];
    const char* bgp[2];
#pragma unroll
    for (int u = 0; u < 2; ++u) {
        int g = 2 * wave + u;
        int rowid = row0 + g * 16 + l16;
        int tok = (MODE == 0) ? pair_token[rowid] : rowid;
        agp[u] = (const char*)A + (size_t)tok * (HD * 2) + quad * 16;
        int col = colb + g * 16 + l16;
        bgp[u] = (const char*)Bw + (((size_t)e << 20) + ((size_t)col << 10)) * 2 + quad * 16;
    }

    vfloat4 acc[4][4];
#pragma unroll
    for (int i = 0; i < 4; ++i)
#pragma unroll
        for (int j = 0; j < 4; ++j)
            acc[i][j] = (vfloat4){0.f, 0.f, 0.f, 0.f};

    for (int k0 = 0; k0 < HD; k0 += 128) {
        __syncthreads();                   // prev tile's reads complete
#pragma unroll
        for (int u = 0; u < 2; ++u) {
            int g = 2 * wave + u;
#pragma unroll
            for (int kc = 0; kc < 4; ++kc) {
                gld16(agp[u] + (size_t)k0 * 2 + kc * 64, smem + (g * 4 + kc) * 512);
                gld16(bgp[u] + (size_t)k0 * 2 + kc * 64, smem + 16384 + (g * 4 + kc) * 512);
            }
        }
        __syncthreads();                   // drain, data visible
#pragma unroll
        for (int s = 0; s < 4; ++s) {
            vshort8 af[4], bfr[4];
#pragma unroll
            for (int i = 0; i < 4; ++i)
                af[i] = *(const vshort8*)(smem + ((wm * 4 + i) * 4 + s) * 512 + lane * 8);
#pragma unroll
            for (int j = 0; j < 4; ++j)
                bfr[j] = *(const vshort8*)(smem + 16384 + ((wn * 4 + j) * 4 + s) * 512 + lane * 8);
#pragma unroll
            for (int i = 0; i < 4; ++i)
#pragma unroll
                for (int j = 0; j < 4; ++j)
                    acc[i][j] = __builtin_amdgcn_mfma_f32_16x16x32_bf16(af[i], bfr[j], acc[i][j], 0, 0, 0);
        }
    }

    if (MODE == 0) {
        // epilogue: relu(acc+b1) -> bf16 LDS tile -> row-major h1 (coalesced)
        __syncthreads();
#pragma unroll
        for (int j = 0; j < 4; ++j) {
            int col = wn * 64 + j * 16 + l16;
            float bv = bias[e * HD + colb + col];
#pragma unroll
            for (int i = 0; i < 4; ++i) {
                int rl = wm * 64 + i * 16 + quad * 4;
#pragma unroll
                for (int reg = 0; reg < 4; ++reg) {
                    float v = acc[i][j][reg] + bv;
                    v = v > 0.f ? v : 0.f;
                    smem[(rl + reg) * EP_LDSW + col] = bf16r(v);
                }
            }
        }
        __syncthreads();
#pragma unroll
        for (int rr = 0; rr < 8; ++rr) {
            int row = rr * 16 + (t >> 4);
            int col = (t & 15) * 8;
            vshort8 v = *(const vshort8*)(smem + row * EP_LDSW + col);
            *(vshort8*)(h1_out + (size_t)(row0 + row) * HD + colb + col) = v;
        }
    } else {
        int tok[4][4]; float wv[4][4];
#pragma unroll
        for (int i = 0; i < 4; ++i)
#pragma unroll
            for (int reg = 0; reg < 4; ++reg) {
                int r = row0 + wm * 64 + i * 16 + quad * 4 + reg;
                tok[i][reg] = pair_token[r];
                wv[i][reg] = pair_w[r];
            }
#pragma unroll
        for (int j = 0; j < 4; ++j) {
            int col = colb + wn * 64 + j * 16 + l16;
            float bv = bias[e * HD + col];
#pragma unroll
            for (int i = 0; i < 4; ++i)
#pragma unroll
                for (int reg = 0; reg < 4; ++reg)
                    if (tok[i][reg] < ZROW)
                        atomicAdd(out + (size_t)tok[i][reg] * HD + col,
                                  wv[i][reg] * (acc[i][j][reg] + bv));
        }
    }
}

extern "C" void kernel_launch(void* const* d_in, const int* in_sizes, int n_in,
                              void* d_out, int out_size, void* d_ws, size_t ws_size,
                              hipStream_t stream) {
    const float* x  = (const float*)d_in[0];
    const float* rw = (const float*)d_in[1];
    const float* W1 = (const float*)d_in[2];
    const float* b1 = (const float*)d_in[3];
    const float* W2 = (const float*)d_in[4];
    const float* b2 = (const float*)d_in[5];
    float* out   = (float*)d_out;                // [8192,1024] residual+moe
    float* probs = out + (size_t)NTOK * HD;      // [8192,8]

    char* ws = (char*)d_ws;
    short* xb = (short*)ws;            ws += (size_t)(NTOK + 1) * HD * 2;
    short* h1 = (short*)ws;            ws += (size_t)MAXP * HD * 2;
    int*   pair_token = (int*)ws;      ws += MAXP * 4;
    float* pair_w     = (float*)ws;    ws += MAXP * 4;
    int*   counts = (int*)ws;          ws += 256;
    int*   fill   = (int*)ws;          ws += 256;
    int2*   tok_top = (int2*)ws;       ws += NTOK * 8;
    float2* tok_w   = (float2*)ws;     ws += NTOK * 8;
    short* w1b = (short*)ws;           ws += (size_t)NEXP * HD * HD * 2;
    short* w2b = (short*)ws;           ws += (size_t)NEXP * HD * HD * 2;
    (void)ws_size;

    init_kernel<<<MAXP / 256, 256, 0, stream>>>(counts, fill, pair_token, xb);
    int cvb = (int)(2 * ((size_t)NEXP * HD * HD / 8) / 256);    // 8192 convert blocks
    prep_kernel<<<RB + cvb, 256, 0, stream>>>(x, rw, W1, W2, out, xb, probs,
                                              tok_top, tok_w, counts, w1b, w2b);
    scatter_kernel<<<NTOK / 256, 256, 0, stream>>>(tok_top, tok_w, counts, fill,
                                                   pair_token, pair_w);
    const int gb = (MAXP / BM) * 8;    // 136 row tiles x 8 col blocks = 1088
    moe_gemm<0><<<gb, 256, 0, stream>>>(xb, w1b, b1, pair_token, pair_w, counts, h1, nullptr);
    moe_gemm<1><<<gb, 256, 0, stream>>>(h1, w2b, b2, pair_token, pair_w, counts, nullptr, out);
}